// Round 2
// baseline (8811.660 us; speedup 1.0000x reference)
//
#include <hip/hip_runtime.h>
#include <cstddef>
#include <cstdint>

// DynamicGPCM: B=4096 sequences, S=512 steps, D=16, K=5, H=256, IN=37.
// Outputs (f32, concat): theta(B,S,16) | alpha(B,S,16) | beta(B,S,4) | logits(B,S,5) | probs(B,S,5)
//
// R2 structure: 1024 blocks x 256 threads, 4 seqs/block.
//  - Phase A (softmax/surprise/u): duplicated per wave (each wave holds all 4 seqs) -> no cross-wave deps.
//  - Phase B (h = tanh(u @ W_h)): lane owns column j = tid; W_h[:,j] in 37 VGPRs (loaded once).
//    u read from per-wave LDS copy as wave-uniform broadcast b128.
//  - Phase C (gate/delta = h @ W_g/W_d): lane owns 32-row j-slice x 1 output column, weights in 32 VGPRs.
//    h read from own wave's LDS slice (2-addr broadcast). shfl_xor(32) pair-reduce, then cross-wave
//    reduce via double-buffered sRed + the single __syncthreads per step.

namespace {
constexpr int Bn = 4096;
constexpr int Sn = 512;
constexpr int Dn = 16;
constexpr int Qn = 1000;

__device__ __forceinline__ float ftanh(float x) {
  return 1.0f - 2.0f / (__expf(2.0f * x) + 1.0f);
}
__device__ __forceinline__ float fsigmoid(float x) {
  return 1.0f / (1.0f + __expf(-x));
}
__device__ __forceinline__ float fsoftplus(float x) {
  return (x > 20.0f) ? x : log1pf(__expf(x));
}

// Intra-wave LDS fence: producer and consumer are the same wave.
#define WAVE_FENCE() asm volatile("s_waitcnt lgkmcnt(0)" ::: "memory")

// ---- Kernel A: per-question item parameters (Q+1 = 1001 rows, tiny) ----
__global__ void precompute_kernel(const float* __restrict__ alpha_raw,
                                  const float* __restrict__ beta_base,
                                  const float* __restrict__ beta_gaps,
                                  float* __restrict__ alpha_q,
                                  float* __restrict__ beta_q) {
  int tid = blockIdx.x * 256 + threadIdx.x;
  if (tid < (Qn + 1) * Dn) alpha_q[tid] = __expf(0.3f * alpha_raw[tid]);
  if (tid < Qn + 1) {
    float base = beta_base[tid];
    float sp0 = fsoftplus(beta_gaps[tid * 3 + 0]);
    float sp1 = fsoftplus(beta_gaps[tid * 3 + 1]);
    float sp2 = fsoftplus(beta_gaps[tid * 3 + 2]);
    beta_q[tid * 4 + 0] = base;
    beta_q[tid * 4 + 1] = base + sp0;
    beta_q[tid * 4 + 2] = base + sp0 + sp1;
    beta_q[tid * 4 + 3] = base + sp0 + sp1 + sp2;
  }
}

// ---- Kernel B: gather alpha/beta output tensors, fully coalesced ----
__global__ void itemout_kernel(const int* __restrict__ questions,
                               const float4* __restrict__ alpha_q4,
                               const float4* __restrict__ beta_q4,
                               float4* __restrict__ out_alpha4,
                               float4* __restrict__ out_beta4) {
  int tid = blockIdx.x * 256 + threadIdx.x;  // [0, B*S*4)
  int pos = tid >> 2, j = tid & 3;
  if (pos >= Bn * Sn) return;
  int q = questions[pos];
  out_alpha4[(size_t)pos * 4 + j] = alpha_q4[(size_t)q * 4 + j];
  if (j == 0) out_beta4[pos] = beta_q4[q];
}

// ---- Kernel C: recurrent scan. 256 threads, 4 seqs/block, 1024 blocks ----
__global__ __launch_bounds__(256, 4) void scan_kernel(
    const float* __restrict__ theta_embed,
    const float* __restrict__ W_h, const float* __restrict__ b_h,
    const float* __restrict__ W_g, const float* __restrict__ b_g,
    const float* __restrict__ W_d, const float* __restrict__ b_d,
    const int* __restrict__ student_ids, const int* __restrict__ questions,
    const int* __restrict__ responses,
    const float* __restrict__ alpha_q, const float4* __restrict__ beta_q4,
    float* __restrict__ out_theta, float* __restrict__ out_logits,
    float* __restrict__ out_probs) {
  __shared__ float sUT[4][38][4];       // per-wave u, transposed: [wave][i][s]
  __shared__ float sH[4][260];          // h: [s][col] (pad 260)
  __shared__ float sRed[2][4][32][4];   // partial gate/delta: [buf][wave][c][s]

  const int tid = threadIdx.x;
  const int d = tid & 15;
  const int st = tid >> 4;          // 0..15
  const int s = st & 3;             // seq within block (each wave holds all 4)
  const int wv = tid >> 6;          // wave 0..3
  const int lane = tid & 63;

  const int b = blockIdx.x * 4 + s;

  // ---- one-time register-resident weights ----
  float wh[37];                     // W_h[:, tid]
#pragma unroll
  for (int i = 0; i < 37; ++i) wh[i] = W_h[i * 256 + tid];
  const float bh = b_h[tid];

  const int c = lane & 31;                         // output column (0..15 gate, 16..31 delta)
  const int jbase = (wv << 6) + ((lane >> 5) << 5); // 32-row j-slice within this wave's 64 cols
  const int cc = c & 15;
  const float* Wm = (c < 16) ? W_g : W_d;
  float wm[32];                     // Wm[jbase+j][cc]
#pragma unroll
  for (int j = 0; j < 32; ++j) wm[j] = Wm[(jbase + j) * 16 + cc];

  const float bg = b_g[d], bdv = b_d[d];

  const int* qrow = questions + (size_t)b * Sn;
  const int* rrow = responses + (size_t)b * Sn;
  float th = theta_embed[(size_t)student_ids[(size_t)b * Sn] * Dn + d];

  // double-prefetched item params: (a,bq) for t, (qn,rn) index for t+1
  int r = rrow[0];
  {
    int q0 = qrow[0];
    // current-step params loaded below via q0
    float a0 = alpha_q[(size_t)q0 * Dn + d];
    float4 bq0 = beta_q4[q0];
    int qn = qrow[1], rn = rrow[1];

    float a = a0;
    float4 bq = bq0;

    for (int t = 0; t < Sn; ++t) {
      // issue t+1 param loads + t+2 index loads early (hide under compute)
      const float an = alpha_q[(size_t)qn * Dn + d];
      const float4 bqn = beta_q4[qn];
      const int t2 = (t + 2 < Sn) ? t + 2 : Sn - 1;
      const int qn2 = qrow[t2];
      const int rn2 = rrow[t2];

      // ---- Phase A: z, softmax, surprise (duplicated per wave) ----
      float z = a * th;
      z += __shfl_xor(z, 1);
      z += __shfl_xor(z, 2);
      z += __shfl_xor(z, 4);
      z += __shfl_xor(z, 8);

      const float l1 = z - bq.x;
      const float l2 = l1 + z - bq.y;
      const float l3 = l2 + z - bq.z;
      const float l4 = l3 + z - bq.w;
      const float m = fmaxf(fmaxf(fmaxf(l1, l2), fmaxf(l3, l4)), 0.0f);
      const float e0 = __expf(-m);
      const float e1 = __expf(l1 - m);
      const float e2 = __expf(l2 - m);
      const float e3 = __expf(l3 - m);
      const float e4 = __expf(l4 - m);
      const float inv = 1.0f / (e0 + e1 + e2 + e3 + e4);
      const float expected = (e1 + 2.0f * e2 + 3.0f * e3 + 4.0f * e4) * inv;
      const float surprise = (float)r - expected;

      // outputs: only wave 0 stores (waves 1-3 are duplicates)
      if (wv == 0) {
        const size_t pos = (size_t)b * Sn + t;
        out_theta[pos * Dn + d] = th;
        if (d < 5) {
          float lv = (d == 0) ? 0.0f : (d == 1) ? l1 : (d == 2) ? l2 : (d == 3) ? l3 : l4;
          float ev = (d == 0) ? e0 : (d == 1) ? e1 : (d == 2) ? e2 : (d == 3) ? e3 : e4;
          out_logits[pos * 5 + d] = lv;
          out_probs[pos * 5 + d] = ev * inv;
        }
      }

      // u = [theta(16), surprise, a(16), beta(4)] -> per-wave transposed copy
      sUT[wv][d][s] = th;
      sUT[wv][17 + d][s] = a;
      if (d == 0) sUT[wv][16][s] = surprise;
      if (d < 4) sUT[wv][33 + d][s] = (d == 0) ? bq.x : (d == 1) ? bq.y : (d == 2) ? bq.z : bq.w;
      WAVE_FENCE();

      // ---- Phase B: h[s][tid] = tanh(bh + sum_i u[s][i]*wh[i]) ----
      float h0 = bh, h1 = bh, h2 = bh, h3 = bh;
#pragma unroll
      for (int i = 0; i < 37; ++i) {
        const float4 u4 = *(const float4*)&sUT[wv][i][0];  // wave-uniform broadcast
        const float w = wh[i];
        h0 += u4.x * w; h1 += u4.y * w; h2 += u4.z * w; h3 += u4.w * w;
      }
      h0 = ftanh(h0); h1 = ftanh(h1); h2 = ftanh(h2); h3 = ftanh(h3);
      sH[0][tid] = h0; sH[1][tid] = h1; sH[2][tid] = h2; sH[3][tid] = h3;
      WAVE_FENCE();

      // ---- Phase C: partial[s] = sum_{j in slice} h[s][jbase+j]*wm[j] ----
      float p0 = 0.0f, p1 = 0.0f, p2 = 0.0f, p3 = 0.0f;
#pragma unroll
      for (int j = 0; j < 32; j += 4) {
        const float4 h0v = *(const float4*)&sH[0][jbase + j];
        const float4 h1v = *(const float4*)&sH[1][jbase + j];
        const float4 h2v = *(const float4*)&sH[2][jbase + j];
        const float4 h3v = *(const float4*)&sH[3][jbase + j];
        p0 += h0v.x * wm[j] + h0v.y * wm[j + 1] + h0v.z * wm[j + 2] + h0v.w * wm[j + 3];
        p1 += h1v.x * wm[j] + h1v.y * wm[j + 1] + h1v.z * wm[j + 2] + h1v.w * wm[j + 3];
        p2 += h2v.x * wm[j] + h2v.y * wm[j + 1] + h2v.z * wm[j + 2] + h2v.w * wm[j + 3];
        p3 += h3v.x * wm[j] + h3v.y * wm[j + 1] + h3v.z * wm[j + 2] + h3v.w * wm[j + 3];
      }
      // pair-reduce across the two 32-row slices of this wave
      p0 += __shfl_xor(p0, 32);
      p1 += __shfl_xor(p1, 32);
      p2 += __shfl_xor(p2, 32);
      p3 += __shfl_xor(p3, 32);
      if (lane < 32) {
        float4 pv; pv.x = p0; pv.y = p1; pv.z = p2; pv.w = p3;
        *(float4*)&sRed[t & 1][wv][c][0] = pv;
      }
      __syncthreads();  // the single cross-wave sync per step

      // ---- Final: gate/delta reduce over waves, theta update ----
      float gs = bg, dsum = bdv;
#pragma unroll
      for (int w2 = 0; w2 < 4; ++w2) {
        gs += sRed[t & 1][w2][d][s];
        dsum += sRed[t & 1][w2][16 + d][s];
      }
      th += fsigmoid(gs) * ftanh(dsum);

      // rotate prefetched state
      a = an; bq = bqn; r = rn;
      qn = qn2; rn = rn2;
    }
  }
}

}  // namespace

extern "C" void kernel_launch(void* const* d_in, const int* in_sizes, int n_in,
                              void* d_out, int out_size, void* d_ws, size_t ws_size,
                              hipStream_t stream) {
  const float* theta_embed = (const float*)d_in[0];
  const float* alpha_raw   = (const float*)d_in[1];
  const float* beta_base   = (const float*)d_in[2];
  const float* beta_gaps   = (const float*)d_in[3];
  const float* W_h = (const float*)d_in[4];
  const float* b_h = (const float*)d_in[5];
  const float* W_g = (const float*)d_in[6];
  const float* b_g = (const float*)d_in[7];
  const float* W_d = (const float*)d_in[8];
  const float* b_d = (const float*)d_in[9];
  const int* student_ids = (const int*)d_in[10];
  const int* questions   = (const int*)d_in[11];
  const int* responses   = (const int*)d_in[12];

  float* out = (float*)d_out;
  float* out_theta  = out;
  float* out_alpha  = out_theta + (size_t)Bn * Sn * Dn;
  float* out_beta   = out_alpha + (size_t)Bn * Sn * Dn;
  float* out_logits = out_beta  + (size_t)Bn * Sn * 4;
  float* out_probs  = out_logits + (size_t)Bn * Sn * 5;

  float* alpha_q = (float*)d_ws;                     // (Q+1)*16 floats
  float* beta_q  = alpha_q + (size_t)(Qn + 1) * Dn;  // (Q+1)*4 floats

  hipLaunchKernelGGL(precompute_kernel, dim3(63), dim3(256), 0, stream,
                     alpha_raw, beta_base, beta_gaps, alpha_q, beta_q);
  hipLaunchKernelGGL(itemout_kernel, dim3((Bn * Sn * 4) / 256), dim3(256), 0, stream,
                     questions, (const float4*)alpha_q, (const float4*)beta_q,
                     (float4*)out_alpha, (float4*)out_beta);
  hipLaunchKernelGGL(scan_kernel, dim3(Bn / 4), dim3(256), 0, stream,
                     theta_embed, W_h, b_h, W_g, b_g, W_d, b_d,
                     student_ids, questions, responses,
                     alpha_q, (const float4*)beta_q,
                     out_theta, out_logits, out_probs);
}

// Round 3
// 2537.138 us; speedup vs baseline: 3.4731x; 3.4731x over previous
//
#include <hip/hip_runtime.h>
#include <cstddef>
#include <cstdint>

// DynamicGPCM: B=4096 sequences, S=512 steps, D=16, K=5, H=256, IN=37.
// Outputs (f32, concat): theta(B,S,16) | alpha(B,S,16) | beta(B,S,4) | logits(B,S,5) | probs(B,S,5)
//
// R3 = R2 structure with the spill fixed: __launch_bounds__(256, 2).
// R2's (256,4) clamped the allocator to 64 VGPRs -> wh[37]+wm[32] spilled to
// scratch -> 24.6 GB HBM fetch/dispatch. (256,2) allows ~120 VGPRs; hardware
// occupancy is then set by ACTUAL usage (<=128 -> 4 waves/SIMD).

namespace {
constexpr int Bn = 4096;
constexpr int Sn = 512;
constexpr int Dn = 16;
constexpr int Qn = 1000;

__device__ __forceinline__ float ftanh(float x) {
  return 1.0f - 2.0f / (__expf(2.0f * x) + 1.0f);
}
__device__ __forceinline__ float fsigmoid(float x) {
  return 1.0f / (1.0f + __expf(-x));
}
__device__ __forceinline__ float fsoftplus(float x) {
  return (x > 20.0f) ? x : log1pf(__expf(x));
}

// Intra-wave LDS fence: producer and consumer are the same wave.
#define WAVE_FENCE() asm volatile("s_waitcnt lgkmcnt(0)" ::: "memory")

// ---- Kernel A: per-question item parameters (Q+1 = 1001 rows, tiny) ----
__global__ void precompute_kernel(const float* __restrict__ alpha_raw,
                                  const float* __restrict__ beta_base,
                                  const float* __restrict__ beta_gaps,
                                  float* __restrict__ alpha_q,
                                  float* __restrict__ beta_q) {
  int tid = blockIdx.x * 256 + threadIdx.x;
  if (tid < (Qn + 1) * Dn) alpha_q[tid] = __expf(0.3f * alpha_raw[tid]);
  if (tid < Qn + 1) {
    float base = beta_base[tid];
    float sp0 = fsoftplus(beta_gaps[tid * 3 + 0]);
    float sp1 = fsoftplus(beta_gaps[tid * 3 + 1]);
    float sp2 = fsoftplus(beta_gaps[tid * 3 + 2]);
    beta_q[tid * 4 + 0] = base;
    beta_q[tid * 4 + 1] = base + sp0;
    beta_q[tid * 4 + 2] = base + sp0 + sp1;
    beta_q[tid * 4 + 3] = base + sp0 + sp1 + sp2;
  }
}

// ---- Kernel B: gather alpha/beta output tensors, fully coalesced ----
__global__ void itemout_kernel(const int* __restrict__ questions,
                               const float4* __restrict__ alpha_q4,
                               const float4* __restrict__ beta_q4,
                               float4* __restrict__ out_alpha4,
                               float4* __restrict__ out_beta4) {
  int tid = blockIdx.x * 256 + threadIdx.x;  // [0, B*S*4)
  int pos = tid >> 2, j = tid & 3;
  if (pos >= Bn * Sn) return;
  int q = questions[pos];
  out_alpha4[(size_t)pos * 4 + j] = alpha_q4[(size_t)q * 4 + j];
  if (j == 0) out_beta4[pos] = beta_q4[q];
}

// ---- Kernel C: recurrent scan. 256 threads, 4 seqs/block, 1024 blocks ----
__global__ __launch_bounds__(256, 2) void scan_kernel(
    const float* __restrict__ theta_embed,
    const float* __restrict__ W_h, const float* __restrict__ b_h,
    const float* __restrict__ W_g, const float* __restrict__ b_g,
    const float* __restrict__ W_d, const float* __restrict__ b_d,
    const int* __restrict__ student_ids, const int* __restrict__ questions,
    const int* __restrict__ responses,
    const float* __restrict__ alpha_q, const float4* __restrict__ beta_q4,
    float* __restrict__ out_theta, float* __restrict__ out_logits,
    float* __restrict__ out_probs) {
  __shared__ float sUT[4][38][4];       // per-wave u, transposed: [wave][i][s]
  __shared__ float sH[4][260];          // h: [s][col] (pad 260)
  __shared__ float sRed[2][4][32][4];   // partial gate/delta: [buf][wave][c][s]

  const int tid = threadIdx.x;
  const int d = tid & 15;
  const int st = tid >> 4;          // 0..15
  const int s = st & 3;             // seq within block (each wave holds all 4)
  const int wv = tid >> 6;          // wave 0..3
  const int lane = tid & 63;

  const int b = blockIdx.x * 4 + s;

  // ---- one-time register-resident weights ----
  float wh[37];                     // W_h[:, tid]
#pragma unroll
  for (int i = 0; i < 37; ++i) wh[i] = W_h[i * 256 + tid];
  const float bh = b_h[tid];

  const int c = lane & 31;                          // output column (0..15 gate, 16..31 delta)
  const int jbase = (wv << 6) + ((lane >> 5) << 5); // 32-row j-slice within this wave's 64 cols
  const int cc = c & 15;
  const float* Wm = (c < 16) ? W_g : W_d;
  float wm[32];                     // Wm[jbase+j][cc]
#pragma unroll
  for (int j = 0; j < 32; ++j) wm[j] = Wm[(jbase + j) * 16 + cc];

  const float bg = b_g[d], bdv = b_d[d];

  const int* qrow = questions + (size_t)b * Sn;
  const int* rrow = responses + (size_t)b * Sn;
  float th = theta_embed[(size_t)student_ids[(size_t)b * Sn] * Dn + d];

  int r = rrow[0];
  {
    int q0 = qrow[0];
    float a0 = alpha_q[(size_t)q0 * Dn + d];
    float4 bq0 = beta_q4[q0];
    int qn = qrow[1], rn = rrow[1];

    float a = a0;
    float4 bq = bq0;

    for (int t = 0; t < Sn; ++t) {
      // issue t+1 param loads + t+2 index loads early (hide under compute)
      const float an = alpha_q[(size_t)qn * Dn + d];
      const float4 bqn = beta_q4[qn];
      const int t2 = (t + 2 < Sn) ? t + 2 : Sn - 1;
      const int qn2 = qrow[t2];
      const int rn2 = rrow[t2];

      // ---- Phase A: z, softmax, surprise (duplicated per wave) ----
      float z = a * th;
      z += __shfl_xor(z, 1);
      z += __shfl_xor(z, 2);
      z += __shfl_xor(z, 4);
      z += __shfl_xor(z, 8);

      const float l1 = z - bq.x;
      const float l2 = l1 + z - bq.y;
      const float l3 = l2 + z - bq.z;
      const float l4 = l3 + z - bq.w;
      const float m = fmaxf(fmaxf(fmaxf(l1, l2), fmaxf(l3, l4)), 0.0f);
      const float e0 = __expf(-m);
      const float e1 = __expf(l1 - m);
      const float e2 = __expf(l2 - m);
      const float e3 = __expf(l3 - m);
      const float e4 = __expf(l4 - m);
      const float inv = 1.0f / (e0 + e1 + e2 + e3 + e4);
      const float expected = (e1 + 2.0f * e2 + 3.0f * e3 + 4.0f * e4) * inv;
      const float surprise = (float)r - expected;

      // outputs: only wave 0 stores (waves 1-3 are duplicates)
      if (wv == 0) {
        const size_t pos = (size_t)b * Sn + t;
        out_theta[pos * Dn + d] = th;
        if (d < 5) {
          float lv = (d == 0) ? 0.0f : (d == 1) ? l1 : (d == 2) ? l2 : (d == 3) ? l3 : l4;
          float ev = (d == 0) ? e0 : (d == 1) ? e1 : (d == 2) ? e2 : (d == 3) ? e3 : e4;
          out_logits[pos * 5 + d] = lv;
          out_probs[pos * 5 + d] = ev * inv;
        }
      }

      // u = [theta(16), surprise, a(16), beta(4)] -> per-wave transposed copy
      sUT[wv][d][s] = th;
      sUT[wv][17 + d][s] = a;
      if (d == 0) sUT[wv][16][s] = surprise;
      if (d < 4) sUT[wv][33 + d][s] = (d == 0) ? bq.x : (d == 1) ? bq.y : (d == 2) ? bq.z : bq.w;
      WAVE_FENCE();

      // ---- Phase B: h[s][tid] = tanh(bh + sum_i u[s][i]*wh[i]) ----
      float h0 = bh, h1 = bh, h2 = bh, h3 = bh;
#pragma unroll
      for (int i = 0; i < 37; ++i) {
        const float4 u4 = *(const float4*)&sUT[wv][i][0];  // wave-uniform broadcast
        const float w = wh[i];
        h0 += u4.x * w; h1 += u4.y * w; h2 += u4.z * w; h3 += u4.w * w;
      }
      h0 = ftanh(h0); h1 = ftanh(h1); h2 = ftanh(h2); h3 = ftanh(h3);
      sH[0][tid] = h0; sH[1][tid] = h1; sH[2][tid] = h2; sH[3][tid] = h3;
      WAVE_FENCE();

      // ---- Phase C: partial[s] = sum_{j in slice} h[s][jbase+j]*wm[j] ----
      float p0 = 0.0f, p1 = 0.0f, p2 = 0.0f, p3 = 0.0f;
#pragma unroll
      for (int j = 0; j < 32; j += 4) {
        const float4 h0v = *(const float4*)&sH[0][jbase + j];
        const float4 h1v = *(const float4*)&sH[1][jbase + j];
        const float4 h2v = *(const float4*)&sH[2][jbase + j];
        const float4 h3v = *(const float4*)&sH[3][jbase + j];
        p0 += h0v.x * wm[j] + h0v.y * wm[j + 1] + h0v.z * wm[j + 2] + h0v.w * wm[j + 3];
        p1 += h1v.x * wm[j] + h1v.y * wm[j + 1] + h1v.z * wm[j + 2] + h1v.w * wm[j + 3];
        p2 += h2v.x * wm[j] + h2v.y * wm[j + 1] + h2v.z * wm[j + 2] + h2v.w * wm[j + 3];
        p3 += h3v.x * wm[j] + h3v.y * wm[j + 1] + h3v.z * wm[j + 2] + h3v.w * wm[j + 3];
      }
      // pair-reduce across the two 32-row slices of this wave
      p0 += __shfl_xor(p0, 32);
      p1 += __shfl_xor(p1, 32);
      p2 += __shfl_xor(p2, 32);
      p3 += __shfl_xor(p3, 32);
      if (lane < 32) {
        float4 pv; pv.x = p0; pv.y = p1; pv.z = p2; pv.w = p3;
        *(float4*)&sRed[t & 1][wv][c][0] = pv;
      }
      __syncthreads();  // the single cross-wave sync per step

      // ---- Final: gate/delta reduce over waves, theta update ----
      float gs = bg, dsum = bdv;
#pragma unroll
      for (int w2 = 0; w2 < 4; ++w2) {
        gs += sRed[t & 1][w2][d][s];
        dsum += sRed[t & 1][w2][16 + d][s];
      }
      th += fsigmoid(gs) * ftanh(dsum);

      // rotate prefetched state
      a = an; bq = bqn; r = rn;
      qn = qn2; rn = rn2;
    }
  }
}

}  // namespace

extern "C" void kernel_launch(void* const* d_in, const int* in_sizes, int n_in,
                              void* d_out, int out_size, void* d_ws, size_t ws_size,
                              hipStream_t stream) {
  const float* theta_embed = (const float*)d_in[0];
  const float* alpha_raw   = (const float*)d_in[1];
  const float* beta_base   = (const float*)d_in[2];
  const float* beta_gaps   = (const float*)d_in[3];
  const float* W_h = (const float*)d_in[4];
  const float* b_h = (const float*)d_in[5];
  const float* W_g = (const float*)d_in[6];
  const float* b_g = (const float*)d_in[7];
  const float* W_d = (const float*)d_in[8];
  const float* b_d = (const float*)d_in[9];
  const int* student_ids = (const int*)d_in[10];
  const int* questions   = (const int*)d_in[11];
  const int* responses   = (const int*)d_in[12];

  float* out = (float*)d_out;
  float* out_theta  = out;
  float* out_alpha  = out_theta + (size_t)Bn * Sn * Dn;
  float* out_beta   = out_alpha + (size_t)Bn * Sn * Dn;
  float* out_logits = out_beta  + (size_t)Bn * Sn * 4;
  float* out_probs  = out_logits + (size_t)Bn * Sn * 5;

  float* alpha_q = (float*)d_ws;                     // (Q+1)*16 floats
  float* beta_q  = alpha_q + (size_t)(Qn + 1) * Dn;  // (Q+1)*4 floats

  hipLaunchKernelGGL(precompute_kernel, dim3(63), dim3(256), 0, stream,
                     alpha_raw, beta_base, beta_gaps, alpha_q, beta_q);
  hipLaunchKernelGGL(itemout_kernel, dim3((Bn * Sn * 4) / 256), dim3(256), 0, stream,
                     questions, (const float4*)alpha_q, (const float4*)beta_q,
                     (float4*)out_alpha, (float4*)out_beta);
  hipLaunchKernelGGL(scan_kernel, dim3(Bn / 4), dim3(256), 0, stream,
                     theta_embed, W_h, b_h, W_g, b_g, W_d, b_d,
                     student_ids, questions, responses,
                     alpha_q, (const float4*)beta_q,
                     out_theta, out_logits, out_probs);
}

// Round 4
// 1245.630 us; speedup vs baseline: 7.0741x; 2.0368x over previous
//
#include <hip/hip_runtime.h>
#include <cstddef>
#include <cstdint>

// DynamicGPCM: B=4096 sequences, S=512 steps, D=16, K=5, H=256, IN=37.
// Outputs (f32, concat): theta(B,S,16) | alpha(B,S,16) | beta(B,S,4) | logits(B,S,5) | probs(B,S,5)
//
// R4: MFMA formulation. Block = 256 thr (4 waves) x 8 seqs, grid 512 (2 blk/CU).
//   Phase B:  H^T(256x16) = Wh^T(256x64) @ U^T(64x16)   [per wave: 64-row slice, 8 MFMA]
//   Phase C:  [G;D]^T(32x16) = Wgd^T(32x256) @ H^T(256x16) [duplicated per wave, 16 MFMA]
// Weights live in registers as A-fragments (32+64 VGPR). U per-wave-private LDS
// (fence only); H shared, double-buffered -> ONE barrier/step. Phase-C D-layout
// (row=d-quad, col=s) == theta ownership -> in-register theta update.
// N=16 seq slots: s 8..15 mirror s-8 (clean duplicates, never stored).

namespace {
constexpr int Bn = 4096;
constexpr int Sn = 512;
constexpr int Qn = 1000;

typedef __attribute__((ext_vector_type(8))) __bf16 bf16x8;
typedef __attribute__((ext_vector_type(4))) float f32x4;
typedef __attribute__((ext_vector_type(4))) unsigned short u16x4;

__device__ __forceinline__ float ftanh(float x) {
  return 1.0f - 2.0f / (__expf(2.0f * x) + 1.0f);
}
__device__ __forceinline__ float fsigmoid(float x) {
  return 1.0f / (1.0f + __expf(-x));
}
__device__ __forceinline__ float fsoftplus(float x) {
  return (x > 20.0f) ? x : log1pf(__expf(x));
}
__device__ __forceinline__ unsigned short f2b(float x) {
  return __builtin_bit_cast(unsigned short, (__bf16)x);
}
// u-column permutation: U cols = [theta 0-15 | a 16-31 | surprise 32 | beta 33-36]
// W_h rows  = [theta 0-15 | surprise 16 | a 17-32 | beta 33-36]
__device__ __forceinline__ int permk(int k) {
  if (k < 16) return k;
  if (k < 32) return k + 1;
  if (k == 32) return 16;
  return k;
}

#define WAVE_FENCE() asm volatile("s_waitcnt lgkmcnt(0)" ::: "memory")
// byte-offset swizzles (XOR row-bits into 16B-block index)
#define USWZ(s_, off_) ((((s_) * 128) + (off_)) ^ (((s_) & 7) << 4))
#define HSWZ(s_, off_) ((((s_) * 512) + (off_)) ^ (((s_) & 7) << 4))

// ---- Kernel A: per-question item parameters ----
__global__ void precompute_kernel(const float* __restrict__ alpha_raw,
                                  const float* __restrict__ beta_base,
                                  const float* __restrict__ beta_gaps,
                                  float* __restrict__ alpha_q,
                                  float* __restrict__ beta_q) {
  int tid = blockIdx.x * 256 + threadIdx.x;
  if (tid < (Qn + 1) * 16) alpha_q[tid] = __expf(0.3f * alpha_raw[tid]);
  if (tid < Qn + 1) {
    float base = beta_base[tid];
    float sp0 = fsoftplus(beta_gaps[tid * 3 + 0]);
    float sp1 = fsoftplus(beta_gaps[tid * 3 + 1]);
    float sp2 = fsoftplus(beta_gaps[tid * 3 + 2]);
    beta_q[tid * 4 + 0] = base;
    beta_q[tid * 4 + 1] = base + sp0;
    beta_q[tid * 4 + 2] = base + sp0 + sp1;
    beta_q[tid * 4 + 3] = base + sp0 + sp1 + sp2;
  }
}

// ---- Kernel B: gather alpha/beta output tensors ----
__global__ void itemout_kernel(const int* __restrict__ questions,
                               const float4* __restrict__ alpha_q4,
                               const float4* __restrict__ beta_q4,
                               float4* __restrict__ out_alpha4,
                               float4* __restrict__ out_beta4) {
  int tid = blockIdx.x * 256 + threadIdx.x;
  int pos = tid >> 2, j = tid & 3;
  if (pos >= Bn * Sn) return;
  int q = questions[pos];
  out_alpha4[(size_t)pos * 4 + j] = alpha_q4[(size_t)q * 4 + j];
  if (j == 0) out_beta4[pos] = beta_q4[q];
}

// ---- Kernel C: MFMA scan ----
__global__ __launch_bounds__(256, 2) void scan_kernel(
    const float* __restrict__ theta_embed,
    const float* __restrict__ W_h, const float* __restrict__ b_h,
    const float* __restrict__ W_g, const float* __restrict__ b_g,
    const float* __restrict__ W_d, const float* __restrict__ b_d,
    const int* __restrict__ student_ids, const int* __restrict__ questions,
    const int* __restrict__ responses,
    const float* __restrict__ alpha_q, const float4* __restrict__ beta_q4,
    float* __restrict__ out_theta, float* __restrict__ out_logits,
    float* __restrict__ out_probs) {
  __shared__ char sU[4 * 2048];   // per-wave U^T staging: [16 s][64 k] bf16, swizzled
  __shared__ char sH[2 * 8192];   // H: [16 s][256 j] bf16, swizzled, double-buffered

  const int tid = threadIdx.x;
  const int lane = tid & 63;
  const int wv = tid >> 6;
  const int s = lane & 15;        // seq slot / MFMA N-col / A-row-within-tile
  const int g = lane >> 4;        // quad group: k-group (frags) & d-quad (C/D rows)
  const int bs = blockIdx.x * 8 + (s & 7);

  char* uB = sU + wv * 2048;
  {  // zero own U copy (pad cols 37..63 must stay 0 forever)
    int4 zz = {0, 0, 0, 0};
    ((int4*)uB)[lane * 2] = zz;
    ((int4*)uB)[lane * 2 + 1] = zz;
  }

  // ---- A-fragments: Wh^T slice for this wave's 64 j-rows ----
  bf16x8 whA[4][2];
#pragma unroll
  for (int m = 0; m < 4; ++m) {
    const int j = 64 * wv + 16 * m + s;
#pragma unroll
    for (int kk = 0; kk < 2; ++kk) {
#pragma unroll
      for (int e = 0; e < 8; ++e) {
        const int k = kk * 32 + g * 8 + e;
        float v = 0.0f;
        if (k < 37) v = W_h[permk(k) * 256 + j];
        whA[m][kk][e] = (__bf16)v;
      }
    }
  }
  // ---- A-fragments: [Wg^T ; Wd^T], full K=256, duplicated per wave ----
  bf16x8 wgdA[2][8];
#pragma unroll
  for (int m = 0; m < 2; ++m) {
    const float* Wm = m ? W_d : W_g;
#pragma unroll
    for (int kk = 0; kk < 8; ++kk) {
#pragma unroll
      for (int e = 0; e < 8; ++e) {
        const int k = kk * 32 + g * 8 + e;
        wgdA[m][kk][e] = (__bf16)Wm[k * 16 + s];
      }
    }
  }
  f32x4 bias_h[4];
#pragma unroll
  for (int m = 0; m < 4; ++m)
    bias_h[m] = *(const f32x4*)(b_h + 64 * wv + 16 * m + 4 * g);
  const f32x4 bias_g = *(const f32x4*)(b_g + 4 * g);
  const f32x4 bias_d = *(const f32x4*)(b_d + 4 * g);

  const int* qrow = questions + (size_t)bs * Sn;
  const int* rrow = responses + (size_t)bs * Sn;

  // theta state: th[r] = theta[s][4g+r] (matches Phase-C D layout!)
  f32x4 th = *(const f32x4*)(theta_embed +
                             (size_t)student_ids[(size_t)bs * Sn] * 16 + 4 * g);

  int r = rrow[0];
  int q0 = qrow[0];
  float4 a4 = *(const float4*)(alpha_q + (size_t)q0 * 16 + 4 * g);
  float4 bq = beta_q4[q0];
  int qn = qrow[1], rn = rrow[1];

  for (int t = 0; t < Sn; ++t) {
    // prefetch t+1 params + t+2 indices
    const float4 a4n = *(const float4*)(alpha_q + (size_t)qn * 16 + 4 * g);
    const float4 bqn = beta_q4[qn];
    const int t2 = (t + 2 < Sn) ? t + 2 : Sn - 1;
    const int qn2 = qrow[t2];
    const int rn2 = rrow[t2];

    // ---- Phase A (f32): z, softmax, surprise ----
    float zp = a4.x * th.x + a4.y * th.y + a4.z * th.z + a4.w * th.w;
    zp += __shfl_xor(zp, 16);
    zp += __shfl_xor(zp, 32);
    const float z = zp;

    const float l1 = z - bq.x;
    const float l2 = l1 + z - bq.y;
    const float l3 = l2 + z - bq.z;
    const float l4 = l3 + z - bq.w;
    const float m = fmaxf(fmaxf(fmaxf(l1, l2), fmaxf(l3, l4)), 0.0f);
    const float e0 = __expf(-m);
    const float e1 = __expf(l1 - m);
    const float e2 = __expf(l2 - m);
    const float e3 = __expf(l3 - m);
    const float e4 = __expf(l4 - m);
    const float inv = 1.0f / (e0 + e1 + e2 + e3 + e4);
    const float expected = (e1 + 2.0f * e2 + 3.0f * e3 + 4.0f * e4) * inv;
    const float surprise = (float)r - expected;

    // ---- outputs: one wave stores per step (all waves hold identical data) ----
    if (wv == (t & 3) && (lane & 8) == 0) {  // s < 8
      const size_t pos = (size_t)bs * Sn + t;
      *(f32x4*)(out_theta + pos * 16 + 4 * g) = th;
      const float lv = (g == 0) ? 0.0f : (g == 1) ? l1 : (g == 2) ? l2 : l3;
      const float pv = ((g == 0) ? e0 : (g == 1) ? e1 : (g == 2) ? e2 : e3) * inv;
      out_logits[pos * 5 + g] = lv;
      out_probs[pos * 5 + g] = pv;
      if (g == 3) {
        out_logits[pos * 5 + 4] = l4;
        out_probs[pos * 5 + 4] = e4 * inv;
      }
    }

    // ---- write U^T (own wave's copy), bf16, swizzled ----
    {
      u16x4 thb = {f2b(th.x), f2b(th.y), f2b(th.z), f2b(th.w)};
      *(u16x4*)(uB + USWZ(s, 8 * g)) = thb;              // theta cols 0-15
      u16x4 ab = {f2b(a4.x), f2b(a4.y), f2b(a4.z), f2b(a4.w)};
      *(u16x4*)(uB + USWZ(s, 32 + 8 * g)) = ab;          // a cols 16-31
      if (g == 0) {
        u16x4 sb = {f2b(surprise), f2b(bq.x), f2b(bq.y), f2b(bq.z)};
        *(u16x4*)(uB + USWZ(s, 64)) = sb;                // cols 32-35
        *(unsigned short*)(uB + USWZ(s, 72)) = f2b(bq.w);  // col 36
      }
    }
    WAVE_FENCE();

    // ---- Phase B: H^T slice = Wh^T @ U^T ----
    const bf16x8 ub0 = *(const bf16x8*)(uB + USWZ(s, 16 * g));
    const bf16x8 ub1 = *(const bf16x8*)(uB + USWZ(s, 64 + 16 * g));
    f32x4 acc0 = bias_h[0], acc1 = bias_h[1], acc2 = bias_h[2], acc3 = bias_h[3];
    acc0 = __builtin_amdgcn_mfma_f32_16x16x32_bf16(whA[0][0], ub0, acc0, 0, 0, 0);
    acc1 = __builtin_amdgcn_mfma_f32_16x16x32_bf16(whA[1][0], ub0, acc1, 0, 0, 0);
    acc2 = __builtin_amdgcn_mfma_f32_16x16x32_bf16(whA[2][0], ub0, acc2, 0, 0, 0);
    acc3 = __builtin_amdgcn_mfma_f32_16x16x32_bf16(whA[3][0], ub0, acc3, 0, 0, 0);
    acc0 = __builtin_amdgcn_mfma_f32_16x16x32_bf16(whA[0][1], ub1, acc0, 0, 0, 0);
    acc1 = __builtin_amdgcn_mfma_f32_16x16x32_bf16(whA[1][1], ub1, acc1, 0, 0, 0);
    acc2 = __builtin_amdgcn_mfma_f32_16x16x32_bf16(whA[2][1], ub1, acc2, 0, 0, 0);
    acc3 = __builtin_amdgcn_mfma_f32_16x16x32_bf16(whA[3][1], ub1, acc3, 0, 0, 0);

    // tanh + pack -> H[s][j] bf16 (lane holds j = 64wv+16m+4g+r, r=0..3)
    char* hB = sH + (t & 1) * 8192;
    {
      u16x4 h0 = {f2b(ftanh(acc0.x)), f2b(ftanh(acc0.y)), f2b(ftanh(acc0.z)), f2b(ftanh(acc0.w))};
      *(u16x4*)(hB + HSWZ(s, 128 * wv + 8 * g)) = h0;
      u16x4 h1 = {f2b(ftanh(acc1.x)), f2b(ftanh(acc1.y)), f2b(ftanh(acc1.z)), f2b(ftanh(acc1.w))};
      *(u16x4*)(hB + HSWZ(s, 128 * wv + 32 + 8 * g)) = h1;
      u16x4 h2 = {f2b(ftanh(acc2.x)), f2b(ftanh(acc2.y)), f2b(ftanh(acc2.z)), f2b(ftanh(acc2.w))};
      *(u16x4*)(hB + HSWZ(s, 128 * wv + 64 + 8 * g)) = h2;
      u16x4 h3 = {f2b(ftanh(acc3.x)), f2b(ftanh(acc3.y)), f2b(ftanh(acc3.z)), f2b(ftanh(acc3.w))};
      *(u16x4*)(hB + HSWZ(s, 128 * wv + 96 + 8 * g)) = h3;
    }
    __syncthreads();  // the one barrier per step (H is double-buffered)

    // ---- Phase C: [gate;delta]^T = Wgd^T @ H^T (duplicated per wave) ----
    f32x4 ag = bias_g, ad = bias_d;
#pragma unroll
    for (int kk = 0; kk < 8; ++kk) {
      const bf16x8 hb = *(const bf16x8*)(hB + HSWZ(s, 64 * kk + 16 * g));
      ag = __builtin_amdgcn_mfma_f32_16x16x32_bf16(wgdA[0][kk], hb, ag, 0, 0, 0);
      ad = __builtin_amdgcn_mfma_f32_16x16x32_bf16(wgdA[1][kk], hb, ad, 0, 0, 0);
    }
    // D layout == theta ownership: update in-register, no exchange
    th.x += fsigmoid(ag.x) * ftanh(ad.x);
    th.y += fsigmoid(ag.y) * ftanh(ad.y);
    th.z += fsigmoid(ag.z) * ftanh(ad.z);
    th.w += fsigmoid(ag.w) * ftanh(ad.w);

    // rotate prefetched state
    a4 = a4n; bq = bqn; r = rn;
    qn = qn2; rn = rn2;
  }
}

}  // namespace

extern "C" void kernel_launch(void* const* d_in, const int* in_sizes, int n_in,
                              void* d_out, int out_size, void* d_ws, size_t ws_size,
                              hipStream_t stream) {
  const float* theta_embed = (const float*)d_in[0];
  const float* alpha_raw   = (const float*)d_in[1];
  const float* beta_base   = (const float*)d_in[2];
  const float* beta_gaps   = (const float*)d_in[3];
  const float* W_h = (const float*)d_in[4];
  const float* b_h = (const float*)d_in[5];
  const float* W_g = (const float*)d_in[6];
  const float* b_g = (const float*)d_in[7];
  const float* W_d = (const float*)d_in[8];
  const float* b_d = (const float*)d_in[9];
  const int* student_ids = (const int*)d_in[10];
  const int* questions   = (const int*)d_in[11];
  const int* responses   = (const int*)d_in[12];

  float* out = (float*)d_out;
  float* out_theta  = out;
  float* out_alpha  = out_theta + (size_t)Bn * Sn * 16;
  float* out_beta   = out_alpha + (size_t)Bn * Sn * 16;
  float* out_logits = out_beta  + (size_t)Bn * Sn * 4;
  float* out_probs  = out_logits + (size_t)Bn * Sn * 5;

  float* alpha_q = (float*)d_ws;                     // (Q+1)*16 floats
  float* beta_q  = alpha_q + (size_t)(Qn + 1) * 16;  // (Q+1)*4 floats

  hipLaunchKernelGGL(precompute_kernel, dim3(63), dim3(256), 0, stream,
                     alpha_raw, beta_base, beta_gaps, alpha_q, beta_q);
  hipLaunchKernelGGL(itemout_kernel, dim3((Bn * Sn * 4) / 256), dim3(256), 0, stream,
                     questions, (const float4*)alpha_q, (const float4*)beta_q,
                     (float4*)out_alpha, (float4*)out_beta);
  hipLaunchKernelGGL(scan_kernel, dim3(Bn / 8), dim3(256), 0, stream,
                     theta_embed, W_h, b_h, W_g, b_g, W_d, b_d,
                     student_ids, questions, responses,
                     alpha_q, (const float4*)beta_q,
                     out_theta, out_logits, out_probs);
}

// Round 5
// 718.826 us; speedup vs baseline: 12.2584x; 1.7329x over previous
//
#include <hip/hip_runtime.h>
#include <cstddef>
#include <cstdint>

// DynamicGPCM: B=4096 sequences, S=512 steps, D=16, K=5, H=256, IN=37.
// Outputs (f32, concat): theta(B,S,16) | alpha(B,S,16) | beta(B,S,4) | logits(B,S,5) | probs(B,S,5)
//
// R5: 512-thread blocks (8 waves) x 16 REAL seqs (no mirrored N-slots), grid 256.
//   Phase B: each wave computes a 32-row slice of H^T (4 MFMA + 8 tanh).
//   Phase C: duplicated per wave (16 MFMA, K=256) -> gate/delta land in theta-owner lanes.
//   All hot-loop divides -> v_rcp_f32 (hipcc default emits ~10-instr precise div).

namespace {
constexpr int Bn = 4096;
constexpr int Sn = 512;
constexpr int Qn = 1000;

typedef __attribute__((ext_vector_type(8))) __bf16 bf16x8;
typedef __attribute__((ext_vector_type(4))) float f32x4;
typedef __attribute__((ext_vector_type(4))) unsigned short u16x4;

__device__ __forceinline__ float frcp(float x) { return __builtin_amdgcn_rcpf(x); }
__device__ __forceinline__ float ftanh(float x) {
  return 1.0f - 2.0f * frcp(__expf(2.0f * x) + 1.0f);
}
__device__ __forceinline__ float fsigmoid(float x) {
  return frcp(1.0f + __expf(-x));
}
__device__ __forceinline__ float fsoftplus(float x) {
  return (x > 20.0f) ? x : log1pf(__expf(x));
}
__device__ __forceinline__ unsigned short f2b(float x) {
  return __builtin_bit_cast(unsigned short, (__bf16)x);
}
// u-column permutation: U cols = [theta 0-15 | a 16-31 | surprise 32 | beta 33-36]
// W_h rows  = [theta 0-15 | surprise 16 | a 17-32 | beta 33-36]
__device__ __forceinline__ int permk(int k) {
  if (k < 16) return k;
  if (k < 32) return k + 1;
  if (k == 32) return 16;
  return k;
}

#define WAVE_FENCE() asm volatile("s_waitcnt lgkmcnt(0)" ::: "memory")
// byte-offset swizzles (XOR row-bits into 16B-block index)
#define USWZ(s_, off_) ((((s_) * 128) + (off_)) ^ (((s_) & 7) << 4))
#define HSWZ(s_, off_) ((((s_) * 512) + (off_)) ^ (((s_) & 7) << 4))

// ---- Kernel A: per-question item parameters ----
__global__ void precompute_kernel(const float* __restrict__ alpha_raw,
                                  const float* __restrict__ beta_base,
                                  const float* __restrict__ beta_gaps,
                                  float* __restrict__ alpha_q,
                                  float* __restrict__ beta_q) {
  int tid = blockIdx.x * 256 + threadIdx.x;
  if (tid < (Qn + 1) * 16) alpha_q[tid] = __expf(0.3f * alpha_raw[tid]);
  if (tid < Qn + 1) {
    float base = beta_base[tid];
    float sp0 = fsoftplus(beta_gaps[tid * 3 + 0]);
    float sp1 = fsoftplus(beta_gaps[tid * 3 + 1]);
    float sp2 = fsoftplus(beta_gaps[tid * 3 + 2]);
    beta_q[tid * 4 + 0] = base;
    beta_q[tid * 4 + 1] = base + sp0;
    beta_q[tid * 4 + 2] = base + sp0 + sp1;
    beta_q[tid * 4 + 3] = base + sp0 + sp1 + sp2;
  }
}

// ---- Kernel B: gather alpha/beta output tensors ----
__global__ void itemout_kernel(const int* __restrict__ questions,
                               const float4* __restrict__ alpha_q4,
                               const float4* __restrict__ beta_q4,
                               float4* __restrict__ out_alpha4,
                               float4* __restrict__ out_beta4) {
  int tid = blockIdx.x * 256 + threadIdx.x;
  int pos = tid >> 2, j = tid & 3;
  if (pos >= Bn * Sn) return;
  int q = questions[pos];
  out_alpha4[(size_t)pos * 4 + j] = alpha_q4[(size_t)q * 4 + j];
  if (j == 0) out_beta4[pos] = beta_q4[q];
}

// ---- Kernel C: MFMA scan. 512 threads (8 waves), 16 seqs/block, grid 256 ----
__global__ __launch_bounds__(512, 2) void scan_kernel(
    const float* __restrict__ theta_embed,
    const float* __restrict__ W_h, const float* __restrict__ b_h,
    const float* __restrict__ W_g, const float* __restrict__ b_g,
    const float* __restrict__ W_d, const float* __restrict__ b_d,
    const int* __restrict__ student_ids, const int* __restrict__ questions,
    const int* __restrict__ responses,
    const float* __restrict__ alpha_q, const float4* __restrict__ beta_q4,
    float* __restrict__ out_theta, float* __restrict__ out_logits,
    float* __restrict__ out_probs) {
  __shared__ char sU[8 * 2048];   // per-wave U^T staging: [16 s][64 k] bf16, swizzled
  __shared__ char sH[2 * 8192];   // H: [16 s][256 j] bf16, swizzled, double-buffered

  const int tid = threadIdx.x;
  const int lane = tid & 63;
  const int wv = tid >> 6;        // 0..7
  const int s = lane & 15;        // seq slot / MFMA N-col / A-row-within-tile (ALL REAL)
  const int g = lane >> 4;        // quad group: k-group (frags) & d-quad (C/D rows)
  const int bs = blockIdx.x * 16 + s;

  char* uB = sU + wv * 2048;
  {  // zero own U copy (pad cols 37..63 must stay 0 forever)
    int4 zz = {0, 0, 0, 0};
    ((int4*)uB)[lane * 2] = zz;
    ((int4*)uB)[lane * 2 + 1] = zz;
  }

  // ---- A-fragments: Wh^T slice for this wave's 32 j-rows ----
  bf16x8 whA[2][2];
#pragma unroll
  for (int m = 0; m < 2; ++m) {
    const int j = 32 * wv + 16 * m + s;
#pragma unroll
    for (int kk = 0; kk < 2; ++kk) {
#pragma unroll
      for (int e = 0; e < 8; ++e) {
        const int k = kk * 32 + g * 8 + e;
        float v = 0.0f;
        if (k < 37) v = W_h[permk(k) * 256 + j];
        whA[m][kk][e] = (__bf16)v;
      }
    }
  }
  // ---- A-fragments: [Wg^T ; Wd^T], full K=256, duplicated per wave ----
  bf16x8 wgdA[2][8];
#pragma unroll
  for (int m = 0; m < 2; ++m) {
    const float* Wm = m ? W_d : W_g;
#pragma unroll
    for (int kk = 0; kk < 8; ++kk) {
#pragma unroll
      for (int e = 0; e < 8; ++e) {
        const int k = kk * 32 + g * 8 + e;
        wgdA[m][kk][e] = (__bf16)Wm[k * 16 + s];
      }
    }
  }
  f32x4 bias_h[2];
#pragma unroll
  for (int m = 0; m < 2; ++m)
    bias_h[m] = *(const f32x4*)(b_h + 32 * wv + 16 * m + 4 * g);
  const f32x4 bias_g = *(const f32x4*)(b_g + 4 * g);
  const f32x4 bias_d = *(const f32x4*)(b_d + 4 * g);

  const int* qrow = questions + (size_t)bs * Sn;
  const int* rrow = responses + (size_t)bs * Sn;

  // theta state: th[r] = theta[s][4g+r] (matches Phase-C D layout)
  f32x4 th = *(const f32x4*)(theta_embed +
                             (size_t)student_ids[(size_t)bs * Sn] * 16 + 4 * g);

  int r = rrow[0];
  int q0 = qrow[0];
  float4 a4 = *(const float4*)(alpha_q + (size_t)q0 * 16 + 4 * g);
  float4 bq = beta_q4[q0];
  int qn = qrow[1], rn = rrow[1];

  for (int t = 0; t < Sn; ++t) {
    // prefetch t+1 params + t+2 indices
    const float4 a4n = *(const float4*)(alpha_q + (size_t)qn * 16 + 4 * g);
    const float4 bqn = beta_q4[qn];
    const int t2 = (t + 2 < Sn) ? t + 2 : Sn - 1;
    const int qn2 = qrow[t2];
    const int rn2 = rrow[t2];

    // ---- Phase A (f32): z, softmax, surprise (replicated per wave) ----
    float zp = a4.x * th.x + a4.y * th.y + a4.z * th.z + a4.w * th.w;
    zp += __shfl_xor(zp, 16);
    zp += __shfl_xor(zp, 32);
    const float z = zp;

    const float l1 = z - bq.x;
    const float l2 = l1 + z - bq.y;
    const float l3 = l2 + z - bq.z;
    const float l4 = l3 + z - bq.w;
    const float m = fmaxf(fmaxf(fmaxf(l1, l2), fmaxf(l3, l4)), 0.0f);
    const float e0 = __expf(-m);
    const float e1 = __expf(l1 - m);
    const float e2 = __expf(l2 - m);
    const float e3 = __expf(l3 - m);
    const float e4 = __expf(l4 - m);
    const float inv = frcp(e0 + e1 + e2 + e3 + e4);
    const float expected = (e1 + 2.0f * e2 + 3.0f * e3 + 4.0f * e4) * inv;
    const float surprise = (float)r - expected;

    // ---- outputs: one wave stores per step (all waves hold identical data) ----
    if (wv == (t & 7)) {
      const size_t pos = (size_t)bs * Sn + t;
      *(f32x4*)(out_theta + pos * 16 + 4 * g) = th;
      const float lv = (g == 0) ? 0.0f : (g == 1) ? l1 : (g == 2) ? l2 : l3;
      const float pv = ((g == 0) ? e0 : (g == 1) ? e1 : (g == 2) ? e2 : e3) * inv;
      out_logits[pos * 5 + g] = lv;
      out_probs[pos * 5 + g] = pv;
      if (g == 3) {
        out_logits[pos * 5 + 4] = l4;
        out_probs[pos * 5 + 4] = e4 * inv;
      }
    }

    // ---- write U^T (own wave's copy), bf16, swizzled ----
    {
      u16x4 thb = {f2b(th.x), f2b(th.y), f2b(th.z), f2b(th.w)};
      *(u16x4*)(uB + USWZ(s, 8 * g)) = thb;              // theta cols 0-15
      u16x4 ab = {f2b(a4.x), f2b(a4.y), f2b(a4.z), f2b(a4.w)};
      *(u16x4*)(uB + USWZ(s, 32 + 8 * g)) = ab;          // a cols 16-31
      if (g == 0) {
        u16x4 sb = {f2b(surprise), f2b(bq.x), f2b(bq.y), f2b(bq.z)};
        *(u16x4*)(uB + USWZ(s, 64)) = sb;                // cols 32-35
        *(unsigned short*)(uB + USWZ(s, 72)) = f2b(bq.w);  // col 36
      }
    }
    WAVE_FENCE();

    // ---- Phase B: 32-row slice of H^T = Wh^T @ U^T ----
    const bf16x8 ub0 = *(const bf16x8*)(uB + USWZ(s, 16 * g));
    const bf16x8 ub1 = *(const bf16x8*)(uB + USWZ(s, 64 + 16 * g));
    f32x4 acc0 = bias_h[0], acc1 = bias_h[1];
    acc0 = __builtin_amdgcn_mfma_f32_16x16x32_bf16(whA[0][0], ub0, acc0, 0, 0, 0);
    acc1 = __builtin_amdgcn_mfma_f32_16x16x32_bf16(whA[1][0], ub0, acc1, 0, 0, 0);
    acc0 = __builtin_amdgcn_mfma_f32_16x16x32_bf16(whA[0][1], ub1, acc0, 0, 0, 0);
    acc1 = __builtin_amdgcn_mfma_f32_16x16x32_bf16(whA[1][1], ub1, acc1, 0, 0, 0);

    // tanh + pack -> H[s][j] bf16 (lane holds j = 32wv+16m+4g+r, r=0..3)
    char* hB = sH + (t & 1) * 8192;
    {
      u16x4 h0 = {f2b(ftanh(acc0.x)), f2b(ftanh(acc0.y)), f2b(ftanh(acc0.z)), f2b(ftanh(acc0.w))};
      *(u16x4*)(hB + HSWZ(s, 64 * wv + 8 * g)) = h0;
      u16x4 h1 = {f2b(ftanh(acc1.x)), f2b(ftanh(acc1.y)), f2b(ftanh(acc1.z)), f2b(ftanh(acc1.w))};
      *(u16x4*)(hB + HSWZ(s, 64 * wv + 32 + 8 * g)) = h1;
    }
    __syncthreads();  // the one barrier per step (H is double-buffered)

    // ---- Phase C: [gate;delta]^T = Wgd^T @ H^T (duplicated per wave) ----
    f32x4 ag = bias_g, ad = bias_d;
#pragma unroll
    for (int kk = 0; kk < 8; ++kk) {
      const bf16x8 hb = *(const bf16x8*)(hB + HSWZ(s, 64 * kk + 16 * g));
      ag = __builtin_amdgcn_mfma_f32_16x16x32_bf16(wgdA[0][kk], hb, ag, 0, 0, 0);
      ad = __builtin_amdgcn_mfma_f32_16x16x32_bf16(wgdA[1][kk], hb, ad, 0, 0, 0);
    }
    // D layout == theta ownership: update in-register, no exchange
    th.x += fsigmoid(ag.x) * ftanh(ad.x);
    th.y += fsigmoid(ag.y) * ftanh(ad.y);
    th.z += fsigmoid(ag.z) * ftanh(ad.z);
    th.w += fsigmoid(ag.w) * ftanh(ad.w);

    // rotate prefetched state
    a4 = a4n; bq = bqn; r = rn;
    qn = qn2; rn = rn2;
  }
}

}  // namespace

extern "C" void kernel_launch(void* const* d_in, const int* in_sizes, int n_in,
                              void* d_out, int out_size, void* d_ws, size_t ws_size,
                              hipStream_t stream) {
  const float* theta_embed = (const float*)d_in[0];
  const float* alpha_raw   = (const float*)d_in[1];
  const float* beta_base   = (const float*)d_in[2];
  const float* beta_gaps   = (const float*)d_in[3];
  const float* W_h = (const float*)d_in[4];
  const float* b_h = (const float*)d_in[5];
  const float* W_g = (const float*)d_in[6];
  const float* b_g = (const float*)d_in[7];
  const float* W_d = (const float*)d_in[8];
  const float* b_d = (const float*)d_in[9];
  const int* student_ids = (const int*)d_in[10];
  const int* questions   = (const int*)d_in[11];
  const int* responses   = (const int*)d_in[12];

  float* out = (float*)d_out;
  float* out_theta  = out;
  float* out_alpha  = out_theta + (size_t)Bn * Sn * 16;
  float* out_beta   = out_alpha + (size_t)Bn * Sn * 16;
  float* out_logits = out_beta  + (size_t)Bn * Sn * 4;
  float* out_probs  = out_logits + (size_t)Bn * Sn * 5;

  float* alpha_q = (float*)d_ws;                     // (Q+1)*16 floats
  float* beta_q  = alpha_q + (size_t)(Qn + 1) * 16;  // (Q+1)*4 floats

  hipLaunchKernelGGL(precompute_kernel, dim3(63), dim3(256), 0, stream,
                     alpha_raw, beta_base, beta_gaps, alpha_q, beta_q);
  hipLaunchKernelGGL(itemout_kernel, dim3((Bn * Sn * 4) / 256), dim3(256), 0, stream,
                     questions, (const float4*)alpha_q, (const float4*)beta_q,
                     (float4*)out_alpha, (float4*)out_beta);
  hipLaunchKernelGGL(scan_kernel, dim3(Bn / 16), dim3(512), 0, stream,
                     theta_embed, W_h, b_h, W_g, b_g, W_d, b_d,
                     student_ids, questions, responses,
                     alpha_q, (const float4*)beta_q,
                     out_theta, out_logits, out_probs);
}

// Round 6
// 610.429 us; speedup vs baseline: 14.4352x; 1.1776x over previous
//
#include <hip/hip_runtime.h>
#include <cstddef>
#include <cstdint>

// DynamicGPCM: B=4096 sequences, S=512 steps, D=16, K=5, H=256, IN=37.
// Outputs (f32, concat): theta(B,S,16) | alpha(B,S,16) | beta(B,S,4) | logits(B,S,5) | probs(B,S,5)
//
// R6: 256-thread blocks (4 waves) x 16 REAL seqs, grid 256 (1 block/CU, 1 wave/SIMD).
// Rationale: 4096 seqs x 16 lanes = 1024 waves of unique state = 1 wave/SIMD chip-wide;
// any extra occupancy is pure replication. R5 replicated Phase A/C/update 8x; this
// halves that to 4x at identical per-seq MFMA/tanh totals.
//   Phase B: each wave computes a 64-row slice of H^T (8 MFMA + 16 tanh).
//   Phase C: duplicated per wave (16 MFMA, K=256) -> gate/delta land in theta-owner lanes.
//   One barrier/step (H double-buffered); U per-wave private (wave fence only).

namespace {
constexpr int Bn = 4096;
constexpr int Sn = 512;
constexpr int Qn = 1000;

typedef __attribute__((ext_vector_type(8))) __bf16 bf16x8;
typedef __attribute__((ext_vector_type(4))) float f32x4;
typedef __attribute__((ext_vector_type(4))) unsigned short u16x4;

__device__ __forceinline__ float frcp(float x) { return __builtin_amdgcn_rcpf(x); }
__device__ __forceinline__ float ftanh(float x) {
  return 1.0f - 2.0f * frcp(__expf(2.0f * x) + 1.0f);
}
__device__ __forceinline__ float fsigmoid(float x) {
  return frcp(1.0f + __expf(-x));
}
__device__ __forceinline__ float fsoftplus(float x) {
  return (x > 20.0f) ? x : log1pf(__expf(x));
}
__device__ __forceinline__ unsigned short f2b(float x) {
  return __builtin_bit_cast(unsigned short, (__bf16)x);
}
// u-column permutation: U cols = [theta 0-15 | a 16-31 | surprise 32 | beta 33-36]
// W_h rows  = [theta 0-15 | surprise 16 | a 17-32 | beta 33-36]
__device__ __forceinline__ int permk(int k) {
  if (k < 16) return k;
  if (k < 32) return k + 1;
  if (k == 32) return 16;
  return k;
}

#define WAVE_FENCE() asm volatile("s_waitcnt lgkmcnt(0)" ::: "memory")
// byte-offset swizzles (XOR row-bits into 16B-block index)
#define USWZ(s_, off_) ((((s_) * 128) + (off_)) ^ (((s_) & 7) << 4))
#define HSWZ(s_, off_) ((((s_) * 512) + (off_)) ^ (((s_) & 7) << 4))

// ---- Kernel A: per-question item parameters ----
__global__ void precompute_kernel(const float* __restrict__ alpha_raw,
                                  const float* __restrict__ beta_base,
                                  const float* __restrict__ beta_gaps,
                                  float* __restrict__ alpha_q,
                                  float* __restrict__ beta_q) {
  int tid = blockIdx.x * 256 + threadIdx.x;
  if (tid < (Qn + 1) * 16) alpha_q[tid] = __expf(0.3f * alpha_raw[tid]);
  if (tid < Qn + 1) {
    float base = beta_base[tid];
    float sp0 = fsoftplus(beta_gaps[tid * 3 + 0]);
    float sp1 = fsoftplus(beta_gaps[tid * 3 + 1]);
    float sp2 = fsoftplus(beta_gaps[tid * 3 + 2]);
    beta_q[tid * 4 + 0] = base;
    beta_q[tid * 4 + 1] = base + sp0;
    beta_q[tid * 4 + 2] = base + sp0 + sp1;
    beta_q[tid * 4 + 3] = base + sp0 + sp1 + sp2;
  }
}

// ---- Kernel B: gather alpha/beta output tensors ----
__global__ void itemout_kernel(const int* __restrict__ questions,
                               const float4* __restrict__ alpha_q4,
                               const float4* __restrict__ beta_q4,
                               float4* __restrict__ out_alpha4,
                               float4* __restrict__ out_beta4) {
  int tid = blockIdx.x * 256 + threadIdx.x;
  int pos = tid >> 2, j = tid & 3;
  if (pos >= Bn * Sn) return;
  int q = questions[pos];
  out_alpha4[(size_t)pos * 4 + j] = alpha_q4[(size_t)q * 4 + j];
  if (j == 0) out_beta4[pos] = beta_q4[q];
}

// ---- Kernel C: MFMA scan. 256 threads (4 waves), 16 seqs/block, grid 256 ----
__global__ __launch_bounds__(256, 1) void scan_kernel(
    const float* __restrict__ theta_embed,
    const float* __restrict__ W_h, const float* __restrict__ b_h,
    const float* __restrict__ W_g, const float* __restrict__ b_g,
    const float* __restrict__ W_d, const float* __restrict__ b_d,
    const int* __restrict__ student_ids, const int* __restrict__ questions,
    const int* __restrict__ responses,
    const float* __restrict__ alpha_q, const float4* __restrict__ beta_q4,
    float* __restrict__ out_theta, float* __restrict__ out_logits,
    float* __restrict__ out_probs) {
  __shared__ char sU[4 * 2048];   // per-wave U^T staging: [16 s][64 k] bf16, swizzled
  __shared__ char sH[2 * 8192];   // H: [16 s][256 j] bf16, swizzled, double-buffered

  const int tid = threadIdx.x;
  const int lane = tid & 63;
  const int wv = tid >> 6;        // 0..3
  const int s = lane & 15;        // seq slot / MFMA N-col (ALL REAL)
  const int g = lane >> 4;        // quad group: k-group (frags) & d-quad (C/D rows)
  const int bs = blockIdx.x * 16 + s;

  char* uB = sU + wv * 2048;
  {  // zero own U copy (pad cols 37..63 must stay 0 forever)
    int4 zz = {0, 0, 0, 0};
    ((int4*)uB)[lane * 2] = zz;
    ((int4*)uB)[lane * 2 + 1] = zz;
  }

  // ---- A-fragments: Wh^T slice for this wave's 64 j-rows ----
  bf16x8 whA[4][2];
#pragma unroll
  for (int m = 0; m < 4; ++m) {
    const int j = 64 * wv + 16 * m + s;
#pragma unroll
    for (int kk = 0; kk < 2; ++kk) {
#pragma unroll
      for (int e = 0; e < 8; ++e) {
        const int k = kk * 32 + g * 8 + e;
        float v = 0.0f;
        if (k < 37) v = W_h[permk(k) * 256 + j];
        whA[m][kk][e] = (__bf16)v;
      }
    }
  }
  // ---- A-fragments: [Wg^T ; Wd^T], full K=256, duplicated per wave ----
  bf16x8 wgdA[2][8];
#pragma unroll
  for (int m = 0; m < 2; ++m) {
    const float* Wm = m ? W_d : W_g;
#pragma unroll
    for (int kk = 0; kk < 8; ++kk) {
#pragma unroll
      for (int e = 0; e < 8; ++e) {
        const int k = kk * 32 + g * 8 + e;
        wgdA[m][kk][e] = (__bf16)Wm[k * 16 + s];
      }
    }
  }
  f32x4 bias_h[4];
#pragma unroll
  for (int m = 0; m < 4; ++m)
    bias_h[m] = *(const f32x4*)(b_h + 64 * wv + 16 * m + 4 * g);
  const f32x4 bias_g = *(const f32x4*)(b_g + 4 * g);
  const f32x4 bias_d = *(const f32x4*)(b_d + 4 * g);

  const int* qrow = questions + (size_t)bs * Sn;
  const int* rrow = responses + (size_t)bs * Sn;

  // theta state: th[r] = theta[s][4g+r] (matches Phase-C D layout)
  f32x4 th = *(const f32x4*)(theta_embed +
                             (size_t)student_ids[(size_t)bs * Sn] * 16 + 4 * g);

  int r = rrow[0];
  int q0 = qrow[0];
  float4 a4 = *(const float4*)(alpha_q + (size_t)q0 * 16 + 4 * g);
  float4 bq = beta_q4[q0];
  int qn = qrow[1], rn = rrow[1];

  for (int t = 0; t < Sn; ++t) {
    // prefetch t+1 params + t+2 indices
    const float4 a4n = *(const float4*)(alpha_q + (size_t)qn * 16 + 4 * g);
    const float4 bqn = beta_q4[qn];
    const int t2 = (t + 2 < Sn) ? t + 2 : Sn - 1;
    const int qn2 = qrow[t2];
    const int rn2 = rrow[t2];

    // ---- Phase A (f32): z, softmax, surprise (replicated per wave) ----
    float zp = a4.x * th.x + a4.y * th.y + a4.z * th.z + a4.w * th.w;
    zp += __shfl_xor(zp, 16);
    zp += __shfl_xor(zp, 32);
    const float z = zp;

    const float l1 = z - bq.x;
    const float l2 = l1 + z - bq.y;
    const float l3 = l2 + z - bq.z;
    const float l4 = l3 + z - bq.w;
    const float m = fmaxf(fmaxf(fmaxf(l1, l2), fmaxf(l3, l4)), 0.0f);
    const float e0 = __expf(-m);
    const float e1 = __expf(l1 - m);
    const float e2 = __expf(l2 - m);
    const float e3 = __expf(l3 - m);
    const float e4 = __expf(l4 - m);
    const float inv = frcp(e0 + e1 + e2 + e3 + e4);
    const float expected = (e1 + 2.0f * e2 + 3.0f * e3 + 4.0f * e4) * inv;
    const float surprise = (float)r - expected;

    // ---- outputs: one wave stores per step (all waves hold identical data) ----
    if (wv == (t & 3)) {
      const size_t pos = (size_t)bs * Sn + t;
      *(f32x4*)(out_theta + pos * 16 + 4 * g) = th;
      const float lv = (g == 0) ? 0.0f : (g == 1) ? l1 : (g == 2) ? l2 : l3;
      const float pv = ((g == 0) ? e0 : (g == 1) ? e1 : (g == 2) ? e2 : e3) * inv;
      out_logits[pos * 5 + g] = lv;
      out_probs[pos * 5 + g] = pv;
      if (g == 3) {
        out_logits[pos * 5 + 4] = l4;
        out_probs[pos * 5 + 4] = e4 * inv;
      }
    }

    // ---- write U^T (own wave's copy), bf16, swizzled ----
    {
      u16x4 thb = {f2b(th.x), f2b(th.y), f2b(th.z), f2b(th.w)};
      *(u16x4*)(uB + USWZ(s, 8 * g)) = thb;              // theta cols 0-15
      u16x4 ab = {f2b(a4.x), f2b(a4.y), f2b(a4.z), f2b(a4.w)};
      *(u16x4*)(uB + USWZ(s, 32 + 8 * g)) = ab;          // a cols 16-31
      if (g == 0) {
        u16x4 sb = {f2b(surprise), f2b(bq.x), f2b(bq.y), f2b(bq.z)};
        *(u16x4*)(uB + USWZ(s, 64)) = sb;                // cols 32-35
        *(unsigned short*)(uB + USWZ(s, 72)) = f2b(bq.w);  // col 36
      }
    }
    WAVE_FENCE();

    // ---- Phase B: 64-row slice of H^T = Wh^T @ U^T (8 MFMA) ----
    const bf16x8 ub0 = *(const bf16x8*)(uB + USWZ(s, 16 * g));
    const bf16x8 ub1 = *(const bf16x8*)(uB + USWZ(s, 64 + 16 * g));
    f32x4 acc0 = bias_h[0], acc1 = bias_h[1], acc2 = bias_h[2], acc3 = bias_h[3];
    acc0 = __builtin_amdgcn_mfma_f32_16x16x32_bf16(whA[0][0], ub0, acc0, 0, 0, 0);
    acc1 = __builtin_amdgcn_mfma_f32_16x16x32_bf16(whA[1][0], ub0, acc1, 0, 0, 0);
    acc2 = __builtin_amdgcn_mfma_f32_16x16x32_bf16(whA[2][0], ub0, acc2, 0, 0, 0);
    acc3 = __builtin_amdgcn_mfma_f32_16x16x32_bf16(whA[3][0], ub0, acc3, 0, 0, 0);
    acc0 = __builtin_amdgcn_mfma_f32_16x16x32_bf16(whA[0][1], ub1, acc0, 0, 0, 0);
    acc1 = __builtin_amdgcn_mfma_f32_16x16x32_bf16(whA[1][1], ub1, acc1, 0, 0, 0);
    acc2 = __builtin_amdgcn_mfma_f32_16x16x32_bf16(whA[2][1], ub1, acc2, 0, 0, 0);
    acc3 = __builtin_amdgcn_mfma_f32_16x16x32_bf16(whA[3][1], ub1, acc3, 0, 0, 0);

    // tanh + pack -> H[s][j] bf16 (lane holds j = 64wv+16m+4g+r, r=0..3)
    char* hB = sH + (t & 1) * 8192;
    {
      u16x4 h0 = {f2b(ftanh(acc0.x)), f2b(ftanh(acc0.y)), f2b(ftanh(acc0.z)), f2b(ftanh(acc0.w))};
      *(u16x4*)(hB + HSWZ(s, 128 * wv + 8 * g)) = h0;
      u16x4 h1 = {f2b(ftanh(acc1.x)), f2b(ftanh(acc1.y)), f2b(ftanh(acc1.z)), f2b(ftanh(acc1.w))};
      *(u16x4*)(hB + HSWZ(s, 128 * wv + 32 + 8 * g)) = h1;
      u16x4 h2 = {f2b(ftanh(acc2.x)), f2b(ftanh(acc2.y)), f2b(ftanh(acc2.z)), f2b(ftanh(acc2.w))};
      *(u16x4*)(hB + HSWZ(s, 128 * wv + 64 + 8 * g)) = h2;
      u16x4 h3 = {f2b(ftanh(acc3.x)), f2b(ftanh(acc3.y)), f2b(ftanh(acc3.z)), f2b(ftanh(acc3.w))};
      *(u16x4*)(hB + HSWZ(s, 128 * wv + 96 + 8 * g)) = h3;
    }
    __syncthreads();  // the one barrier per step (H is double-buffered)

    // ---- Phase C: [gate;delta]^T = Wgd^T @ H^T (duplicated per wave) ----
    f32x4 ag = bias_g, ad = bias_d;
#pragma unroll
    for (int kk = 0; kk < 8; ++kk) {
      const bf16x8 hb = *(const bf16x8*)(hB + HSWZ(s, 64 * kk + 16 * g));
      ag = __builtin_amdgcn_mfma_f32_16x16x32_bf16(wgdA[0][kk], hb, ag, 0, 0, 0);
      ad = __builtin_amdgcn_mfma_f32_16x16x32_bf16(wgdA[1][kk], hb, ad, 0, 0, 0);
    }
    // D layout == theta ownership: update in-register, no exchange
    th.x += fsigmoid(ag.x) * ftanh(ad.x);
    th.y += fsigmoid(ag.y) * ftanh(ad.y);
    th.z += fsigmoid(ag.z) * ftanh(ad.z);
    th.w += fsigmoid(ag.w) * ftanh(ad.w);

    // rotate prefetched state
    a4 = a4n; bq = bqn; r = rn;
    qn = qn2; rn = rn2;
  }
}

}  // namespace

extern "C" void kernel_launch(void* const* d_in, const int* in_sizes, int n_in,
                              void* d_out, int out_size, void* d_ws, size_t ws_size,
                              hipStream_t stream) {
  const float* theta_embed = (const float*)d_in[0];
  const float* alpha_raw   = (const float*)d_in[1];
  const float* beta_base   = (const float*)d_in[2];
  const float* beta_gaps   = (const float*)d_in[3];
  const float* W_h = (const float*)d_in[4];
  const float* b_h = (const float*)d_in[5];
  const float* W_g = (const float*)d_in[6];
  const float* b_g = (const float*)d_in[7];
  const float* W_d = (const float*)d_in[8];
  const float* b_d = (const float*)d_in[9];
  const int* student_ids = (const int*)d_in[10];
  const int* questions   = (const int*)d_in[11];
  const int* responses   = (const int*)d_in[12];

  float* out = (float*)d_out;
  float* out_theta  = out;
  float* out_alpha  = out_theta + (size_t)Bn * Sn * 16;
  float* out_beta   = out_alpha + (size_t)Bn * Sn * 16;
  float* out_logits = out_beta  + (size_t)Bn * Sn * 4;
  float* out_probs  = out_logits + (size_t)Bn * Sn * 5;

  float* alpha_q = (float*)d_ws;                     // (Q+1)*16 floats
  float* beta_q  = alpha_q + (size_t)(Qn + 1) * 16;  // (Q+1)*4 floats

  hipLaunchKernelGGL(precompute_kernel, dim3(63), dim3(256), 0, stream,
                     alpha_raw, beta_base, beta_gaps, alpha_q, beta_q);
  hipLaunchKernelGGL(itemout_kernel, dim3((Bn * Sn * 4) / 256), dim3(256), 0, stream,
                     questions, (const float4*)alpha_q, (const float4*)beta_q,
                     (float4*)out_alpha, (float4*)out_beta);
  hipLaunchKernelGGL(scan_kernel, dim3(Bn / 16), dim3(256), 0, stream,
                     theta_embed, W_h, b_h, W_g, b_g, W_d, b_d,
                     student_ids, questions, responses,
                     alpha_q, (const float4*)beta_q,
                     out_theta, out_logits, out_probs);
}

// Round 7
// 609.152 us; speedup vs baseline: 14.4655x; 1.0021x over previous
//
#include <hip/hip_runtime.h>
#include <cstddef>
#include <cstdint>

// DynamicGPCM: B=4096 sequences, S=512 steps, D=16, K=5, H=256, IN=37.
// Outputs (f32, concat): theta(B,S,16) | alpha(B,S,16) | beta(B,S,4) | logits(B,S,5) | probs(B,S,5)
//
// R7 = R6 structure (4 waves x 16 seqs, grid 256, 1 wave/SIMD) with:
//  - padded LDS strides (U 144B/row, H 528B/row) -> bank-conflict-free, XOR swizzle dropped
//  - lgkm-only barrier (no vmcnt(0) drain of global prefetches every step)
//  - exp2-folded tanh/sigmoid (v_exp_f32 computes 2^x; fold ln2 into the scale constant)
//  - Phase C as 4 parallel 4-deep MFMA chains (latency exposure halved at 1 wave/SIMD)

namespace {
constexpr int Bn = 4096;
constexpr int Sn = 512;
constexpr int Qn = 1000;

constexpr int UST = 144;   // U row stride in bytes (36 dwords % 32 banks -> rows phase by 4 banks)
constexpr int HST = 528;   // H row stride in bytes (132 dwords % 32 -> rows phase by 4 banks)

typedef __attribute__((ext_vector_type(8))) __bf16 bf16x8;
typedef __attribute__((ext_vector_type(4))) float f32x4;
typedef __attribute__((ext_vector_type(4))) unsigned short u16x4;

__device__ __forceinline__ float frcp(float x) { return __builtin_amdgcn_rcpf(x); }
__device__ __forceinline__ float fexp2(float x) {
  float r;
  asm("v_exp_f32 %0, %1" : "=v"(r) : "v"(x));
  return r;
}
// tanh(x) = 1 - 2/(e^{2x}+1);  e^{2x} = 2^{x*2*log2(e)}
__device__ __forceinline__ float ftanh(float x) {
  return 1.0f - 2.0f * frcp(fexp2(x * 2.88539008177793f) + 1.0f);
}
// sigmoid(x) = 1/(1+e^{-x});  e^{-x} = 2^{-x*log2(e)}
__device__ __forceinline__ float fsigmoid(float x) {
  return frcp(1.0f + fexp2(x * -1.44269504088896f));
}
__device__ __forceinline__ float fsoftplus(float x) {
  return (x > 20.0f) ? x : log1pf(__expf(x));
}
__device__ __forceinline__ unsigned short f2b(float x) {
  return __builtin_bit_cast(unsigned short, (__bf16)x);
}
// u-column permutation: U cols = [theta 0-15 | a 16-31 | surprise 32 | beta 33-36]
// W_h rows  = [theta 0-15 | surprise 16 | a 17-32 | beta 33-36]
__device__ __forceinline__ int permk(int k) {
  if (k < 16) return k;
  if (k < 32) return k + 1;
  if (k == 32) return 16;
  return k;
}

#define WAVE_FENCE() asm volatile("s_waitcnt lgkmcnt(0)" ::: "memory")
// LDS-only barrier: wait own LDS ops, hit the barrier, block hoisting after.
// (No vmcnt(0) drain -> global prefetches stay in flight across the barrier.)
#define BLOCK_SYNC()                                        \
  do {                                                      \
    asm volatile("s_waitcnt lgkmcnt(0)" ::: "memory");      \
    __builtin_amdgcn_s_barrier();                           \
    asm volatile("" ::: "memory");                          \
  } while (0)

// ---- Kernel A: per-question item parameters ----
__global__ void precompute_kernel(const float* __restrict__ alpha_raw,
                                  const float* __restrict__ beta_base,
                                  const float* __restrict__ beta_gaps,
                                  float* __restrict__ alpha_q,
                                  float* __restrict__ beta_q) {
  int tid = blockIdx.x * 256 + threadIdx.x;
  if (tid < (Qn + 1) * 16) alpha_q[tid] = __expf(0.3f * alpha_raw[tid]);
  if (tid < Qn + 1) {
    float base = beta_base[tid];
    float sp0 = fsoftplus(beta_gaps[tid * 3 + 0]);
    float sp1 = fsoftplus(beta_gaps[tid * 3 + 1]);
    float sp2 = fsoftplus(beta_gaps[tid * 3 + 2]);
    beta_q[tid * 4 + 0] = base;
    beta_q[tid * 4 + 1] = base + sp0;
    beta_q[tid * 4 + 2] = base + sp0 + sp1;
    beta_q[tid * 4 + 3] = base + sp0 + sp1 + sp2;
  }
}

// ---- Kernel B: gather alpha/beta output tensors ----
__global__ void itemout_kernel(const int* __restrict__ questions,
                               const float4* __restrict__ alpha_q4,
                               const float4* __restrict__ beta_q4,
                               float4* __restrict__ out_alpha4,
                               float4* __restrict__ out_beta4) {
  int tid = blockIdx.x * 256 + threadIdx.x;
  int pos = tid >> 2, j = tid & 3;
  if (pos >= Bn * Sn) return;
  int q = questions[pos];
  out_alpha4[(size_t)pos * 4 + j] = alpha_q4[(size_t)q * 4 + j];
  if (j == 0) out_beta4[pos] = beta_q4[q];
}

// ---- Kernel C: MFMA scan. 256 threads (4 waves), 16 seqs/block, grid 256 ----
__global__ __launch_bounds__(256, 1) void scan_kernel(
    const float* __restrict__ theta_embed,
    const float* __restrict__ W_h, const float* __restrict__ b_h,
    const float* __restrict__ W_g, const float* __restrict__ b_g,
    const float* __restrict__ W_d, const float* __restrict__ b_d,
    const int* __restrict__ student_ids, const int* __restrict__ questions,
    const int* __restrict__ responses,
    const float* __restrict__ alpha_q, const float4* __restrict__ beta_q4,
    float* __restrict__ out_theta, float* __restrict__ out_logits,
    float* __restrict__ out_probs) {
  __shared__ char sU[4 * 16 * UST];   // per-wave U^T: [16 s][64 k] bf16, row stride 144B
  __shared__ char sH[2 * 16 * HST];   // H: [16 s][256 j] bf16, row stride 528B, dbuf

  const int tid = threadIdx.x;
  const int lane = tid & 63;
  const int wv = tid >> 6;        // 0..3
  const int s = lane & 15;        // seq slot / MFMA N-col (ALL REAL)
  const int g = lane >> 4;        // quad group: k-group (frags) & d-quad (C/D rows)
  const int bs = blockIdx.x * 16 + s;

  char* uB = sU + wv * (16 * UST);
  {  // zero the used 128B of each U row (pad cols 37..63 must stay 0 forever)
    int4 zz = {0, 0, 0, 0};
    char* p = uB + (lane >> 2) * UST + (lane & 3) * 32;
    *(int4*)p = zz;
    *(int4*)(p + 16) = zz;
  }

  // ---- A-fragments: Wh^T slice for this wave's 64 j-rows ----
  bf16x8 whA[4][2];
#pragma unroll
  for (int m = 0; m < 4; ++m) {
    const int j = 64 * wv + 16 * m + s;
#pragma unroll
    for (int kk = 0; kk < 2; ++kk) {
#pragma unroll
      for (int e = 0; e < 8; ++e) {
        const int k = kk * 32 + g * 8 + e;
        float v = 0.0f;
        if (k < 37) v = W_h[permk(k) * 256 + j];
        whA[m][kk][e] = (__bf16)v;
      }
    }
  }
  // ---- A-fragments: [Wg^T ; Wd^T], full K=256, duplicated per wave ----
  bf16x8 wgdA[2][8];
#pragma unroll
  for (int m = 0; m < 2; ++m) {
    const float* Wm = m ? W_d : W_g;
#pragma unroll
    for (int kk = 0; kk < 8; ++kk) {
#pragma unroll
      for (int e = 0; e < 8; ++e) {
        const int k = kk * 32 + g * 8 + e;
        wgdA[m][kk][e] = (__bf16)Wm[k * 16 + s];
      }
    }
  }
  f32x4 bias_h[4];
#pragma unroll
  for (int m = 0; m < 4; ++m)
    bias_h[m] = *(const f32x4*)(b_h + 64 * wv + 16 * m + 4 * g);
  const f32x4 bias_g = *(const f32x4*)(b_g + 4 * g);
  const f32x4 bias_d = *(const f32x4*)(b_d + 4 * g);
  const f32x4 zero4 = {0.0f, 0.0f, 0.0f, 0.0f};

  const int* qrow = questions + (size_t)bs * Sn;
  const int* rrow = responses + (size_t)bs * Sn;

  // theta state: th[r] = theta[s][4g+r] (matches Phase-C D layout)
  f32x4 th = *(const f32x4*)(theta_embed +
                             (size_t)student_ids[(size_t)bs * Sn] * 16 + 4 * g);

  int r = rrow[0];
  int q0 = qrow[0];
  float4 a4 = *(const float4*)(alpha_q + (size_t)q0 * 16 + 4 * g);
  float4 bq = beta_q4[q0];
  int qn = qrow[1], rn = rrow[1];

#pragma unroll 2
  for (int t = 0; t < Sn; ++t) {
    // prefetch t+1 params + t+2 indices (stay in flight across the lgkm-only barrier)
    const float4 a4n = *(const float4*)(alpha_q + (size_t)qn * 16 + 4 * g);
    const float4 bqn = beta_q4[qn];
    const int t2 = (t + 2 < Sn) ? t + 2 : Sn - 1;
    const int qn2 = qrow[t2];
    const int rn2 = rrow[t2];

    // ---- Phase A (f32): z, softmax, surprise (replicated per wave) ----
    float zp = a4.x * th.x + a4.y * th.y + a4.z * th.z + a4.w * th.w;
    zp += __shfl_xor(zp, 16);
    zp += __shfl_xor(zp, 32);
    const float z = zp;

    const float l1 = z - bq.x;
    const float l2 = l1 + z - bq.y;
    const float l3 = l2 + z - bq.z;
    const float l4 = l3 + z - bq.w;
    const float m = fmaxf(fmaxf(fmaxf(l1, l2), fmaxf(l3, l4)), 0.0f);
    const float e0 = fexp2(-m * 1.44269504088896f);
    const float e1 = fexp2((l1 - m) * 1.44269504088896f);
    const float e2 = fexp2((l2 - m) * 1.44269504088896f);
    const float e3 = fexp2((l3 - m) * 1.44269504088896f);
    const float e4 = fexp2((l4 - m) * 1.44269504088896f);
    const float inv = frcp(e0 + e1 + e2 + e3 + e4);
    const float expected = (e1 + 2.0f * e2 + 3.0f * e3 + 4.0f * e4) * inv;
    const float surprise = (float)r - expected;

    // ---- outputs: one wave stores per step (all waves hold identical data) ----
    if (wv == (t & 3)) {
      const size_t pos = (size_t)bs * Sn + t;
      *(f32x4*)(out_theta + pos * 16 + 4 * g) = th;
      const float lv = (g == 0) ? 0.0f : (g == 1) ? l1 : (g == 2) ? l2 : l3;
      const float pv = ((g == 0) ? e0 : (g == 1) ? e1 : (g == 2) ? e2 : e3) * inv;
      out_logits[pos * 5 + g] = lv;
      out_probs[pos * 5 + g] = pv;
      if (g == 3) {
        out_logits[pos * 5 + 4] = l4;
        out_probs[pos * 5 + 4] = e4 * inv;
      }
    }

    // ---- write U^T (own wave's copy), bf16 ----
    {
      char* ur = uB + s * UST;
      u16x4 thb = {f2b(th.x), f2b(th.y), f2b(th.z), f2b(th.w)};
      *(u16x4*)(ur + 8 * g) = thb;                       // theta cols 0-15
      u16x4 ab = {f2b(a4.x), f2b(a4.y), f2b(a4.z), f2b(a4.w)};
      *(u16x4*)(ur + 32 + 8 * g) = ab;                   // a cols 16-31
      if (g == 0) {
        u16x4 sb = {f2b(surprise), f2b(bq.x), f2b(bq.y), f2b(bq.z)};
        *(u16x4*)(ur + 64) = sb;                         // cols 32-35
        *(unsigned short*)(ur + 72) = f2b(bq.w);         // col 36
      }
    }
    WAVE_FENCE();

    // ---- Phase B: 64-row slice of H^T = Wh^T @ U^T (8 MFMA, 4 parallel accs) ----
    const bf16x8 ub0 = *(const bf16x8*)(uB + s * UST + 16 * g);
    const bf16x8 ub1 = *(const bf16x8*)(uB + s * UST + 64 + 16 * g);
    f32x4 acc0 = __builtin_amdgcn_mfma_f32_16x16x32_bf16(whA[0][0], ub0, bias_h[0], 0, 0, 0);
    f32x4 acc1 = __builtin_amdgcn_mfma_f32_16x16x32_bf16(whA[1][0], ub0, bias_h[1], 0, 0, 0);
    f32x4 acc2 = __builtin_amdgcn_mfma_f32_16x16x32_bf16(whA[2][0], ub0, bias_h[2], 0, 0, 0);
    f32x4 acc3 = __builtin_amdgcn_mfma_f32_16x16x32_bf16(whA[3][0], ub0, bias_h[3], 0, 0, 0);
    acc0 = __builtin_amdgcn_mfma_f32_16x16x32_bf16(whA[0][1], ub1, acc0, 0, 0, 0);
    acc1 = __builtin_amdgcn_mfma_f32_16x16x32_bf16(whA[1][1], ub1, acc1, 0, 0, 0);
    acc2 = __builtin_amdgcn_mfma_f32_16x16x32_bf16(whA[2][1], ub1, acc2, 0, 0, 0);
    acc3 = __builtin_amdgcn_mfma_f32_16x16x32_bf16(whA[3][1], ub1, acc3, 0, 0, 0);

    // tanh + pack -> H[s][j] bf16 (lane holds j = 64wv+16m+4g+r, r=0..3)
    char* hB = sH + (t & 1) * (16 * HST);
    {
      char* hr = hB + s * HST + 128 * wv + 8 * g;
      u16x4 h0 = {f2b(ftanh(acc0.x)), f2b(ftanh(acc0.y)), f2b(ftanh(acc0.z)), f2b(ftanh(acc0.w))};
      *(u16x4*)(hr) = h0;
      u16x4 h1 = {f2b(ftanh(acc1.x)), f2b(ftanh(acc1.y)), f2b(ftanh(acc1.z)), f2b(ftanh(acc1.w))};
      *(u16x4*)(hr + 32) = h1;
      u16x4 h2 = {f2b(ftanh(acc2.x)), f2b(ftanh(acc2.y)), f2b(ftanh(acc2.z)), f2b(ftanh(acc2.w))};
      *(u16x4*)(hr + 64) = h2;
      u16x4 h3 = {f2b(ftanh(acc3.x)), f2b(ftanh(acc3.y)), f2b(ftanh(acc3.z)), f2b(ftanh(acc3.w))};
      *(u16x4*)(hr + 96) = h3;
    }
    BLOCK_SYNC();  // lgkm-only barrier (H is double-buffered)

    // ---- Phase C: [gate;delta]^T = Wgd^T @ H^T, 4 parallel 4-deep chains ----
    const char* hr = hB + s * HST + 16 * g;
    f32x4 ag0 = bias_g, ad0 = bias_d, ag1 = zero4, ad1 = zero4;
#pragma unroll
    for (int kk = 0; kk < 4; ++kk) {
      const bf16x8 hb = *(const bf16x8*)(hr + 64 * kk);
      ag0 = __builtin_amdgcn_mfma_f32_16x16x32_bf16(wgdA[0][kk], hb, ag0, 0, 0, 0);
      ad0 = __builtin_amdgcn_mfma_f32_16x16x32_bf16(wgdA[1][kk], hb, ad0, 0, 0, 0);
    }
#pragma unroll
    for (int kk = 4; kk < 8; ++kk) {
      const bf16x8 hb = *(const bf16x8*)(hr + 64 * kk);
      ag1 = __builtin_amdgcn_mfma_f32_16x16x32_bf16(wgdA[0][kk], hb, ag1, 0, 0, 0);
      ad1 = __builtin_amdgcn_mfma_f32_16x16x32_bf16(wgdA[1][kk], hb, ad1, 0, 0, 0);
    }
    const f32x4 ag = ag0 + ag1;
    const f32x4 ad = ad0 + ad1;
    // D layout == theta ownership: update in-register, no exchange
    th.x += fsigmoid(ag.x) * ftanh(ad.x);
    th.y += fsigmoid(ag.y) * ftanh(ad.y);
    th.z += fsigmoid(ag.z) * ftanh(ad.z);
    th.w += fsigmoid(ag.w) * ftanh(ad.w);

    // rotate prefetched state
    a4 = a4n; bq = bqn; r = rn;
    qn = qn2; rn = rn2;
  }
}

}  // namespace

extern "C" void kernel_launch(void* const* d_in, const int* in_sizes, int n_in,
                              void* d_out, int out_size, void* d_ws, size_t ws_size,
                              hipStream_t stream) {
  const float* theta_embed = (const float*)d_in[0];
  const float* alpha_raw   = (const float*)d_in[1];
  const float* beta_base   = (const float*)d_in[2];
  const float* beta_gaps   = (const float*)d_in[3];
  const float* W_h = (const float*)d_in[4];
  const float* b_h = (const float*)d_in[5];
  const float* W_g = (const float*)d_in[6];
  const float* b_g = (const float*)d_in[7];
  const float* W_d = (const float*)d_in[8];
  const float* b_d = (const float*)d_in[9];
  const int* student_ids = (const int*)d_in[10];
  const int* questions   = (const int*)d_in[11];
  const int* responses   = (const int*)d_in[12];

  float* out = (float*)d_out;
  float* out_theta  = out;
  float* out_alpha  = out_theta + (size_t)Bn * Sn * 16;
  float* out_beta   = out_alpha + (size_t)Bn * Sn * 16;
  float* out_logits = out_beta  + (size_t)Bn * Sn * 4;
  float* out_probs  = out_logits + (size_t)Bn * Sn * 5;

  float* alpha_q = (float*)d_ws;                     // (Q+1)*16 floats
  float* beta_q  = alpha_q + (size_t)(Qn + 1) * 16;  // (Q+1)*4 floats

  hipLaunchKernelGGL(precompute_kernel, dim3(63), dim3(256), 0, stream,
                     alpha_raw, beta_base, beta_gaps, alpha_q, beta_q);
  hipLaunchKernelGGL(itemout_kernel, dim3((Bn * Sn * 4) / 256), dim3(256), 0, stream,
                     questions, (const float4*)alpha_q, (const float4*)beta_q,
                     (float4*)out_alpha, (float4*)out_beta);
  hipLaunchKernelGGL(scan_kernel, dim3(Bn / 16), dim3(256), 0, stream,
                     theta_embed, W_h, b_h, W_g, b_g, W_d, b_d,
                     student_ids, questions, responses,
                     alpha_q, (const float4*)beta_q,
                     out_theta, out_logits, out_probs);
}